// Round 12
// baseline (135.012 us; speedup 1.0000x reference)
//
#include <hip/hip_runtime.h>
#include <hip/hip_bf16.h>
#include <cstdint>
#include <cstddef>

// Problem constants (fixed by setup_inputs)
#define IN_F   512
#define OUT_F  512
#define KBASIS 8
#define BATCH  8192
#define KDIM   (IN_F * KBASIS)   // 4096

// GEMM tiling: 512 blocks (2/CU), 512 threads (8 waves = 4 N-cols x 2 K-halves)
// Tile 32M x 256N x 128K per step, 32 steps.
#define BM 32
#define BN 256
#define NSTEPS 32                 // 128 kdim (16 features) per step
#define NTHREADS 512

typedef __attribute__((ext_vector_type(8))) short  short8;   // bf16x8 MFMA frag
typedef __attribute__((ext_vector_type(4))) float  f32x4;
typedef __attribute__((ext_vector_type(4))) unsigned int u32x4;

static __device__ __forceinline__ unsigned short f2bf16(float f) {
    union { float f; unsigned u; } v; v.f = f;
    unsigned u = v.u;
    return (unsigned short)((u + 0x7FFFu + ((u >> 16) & 1u)) >> 16);  // RNE
}

static __device__ __forceinline__ unsigned cvtpk(float lo, float hi) {
    unsigned r;
    asm("v_cvt_pk_bf16_f32 %0, %1, %2" : "=v"(r) : "v"(lo), "v"(hi));
    return r;
}

// ---------------- prep 1: per-feature table, interleaved float4 ----------
// basis_{i,k}(x) = rcp(1 + e_k), e_k = exp2(KA_i*x + KB0_i) * RR_i^k
__global__ void prep_tabs(const float* __restrict__ raw_alpha,
                          const float* __restrict__ beta,
                          const float* __restrict__ centers,
                          const float* __restrict__ slopes,
                          float4* __restrict__ Tab) {
    int i = blockIdx.x * blockDim.x + threadIdx.x;
    if (i >= IN_F) return;
    float ra = raw_alpha[i];
    float sp = (ra > 20.f) ? ra : log1pf(expf(ra));   // softplus
    float alpha = sp + 1e-6f;
    const float NEG2LOG2E = -2.8853900817779268f;     // -2*log2(e)
    float s0 = slopes[i * KBASIS + 0], c0 = centers[i * KBASIS + 0];
    float s1 = slopes[i * KBASIS + 1], c1 = centers[i * KBASIS + 1];
    float kb0 = NEG2LOG2E * s0 * (beta[i] - c0);
    float kb1 = NEG2LOG2E * s1 * (beta[i] - c1);
    float4 t;
    t.x = NEG2LOG2E * s0 * alpha;   // KA
    t.y = kb0;                      // KB0
    t.z = exp2f(kb1 - kb0);         // RR
    t.w = 0.f;
    Tab[i] = t;
}

// ---------------- prep 2: coeffs fp32 -> bf16, TRANSPOSED chunk-major ------
// Wb2[chunk][o][8] where chunk = k/8: B-frag loads are 16B contiguous rows.
__global__ void prep_wbt(const float* __restrict__ w,
                         unsigned short* __restrict__ wb2) {
    int tid = blockIdx.x * blockDim.x + threadIdx.x;   // 262144 threads
    int chunk = tid >> 9;          // 0..511
    int o     = tid & 511;         // 0..511
    const float* src = w + (size_t)o * KDIM + chunk * 8;
    float4 v0 = *(const float4*)src;
    float4 v1 = *(const float4*)(src + 4);
    union { ushort4 u4[2]; unsigned short us[8]; } r;
    r.us[0] = f2bf16(v0.x); r.us[1] = f2bf16(v0.y);
    r.us[2] = f2bf16(v0.z); r.us[3] = f2bf16(v0.w);
    r.us[4] = f2bf16(v1.x); r.us[5] = f2bf16(v1.y);
    r.us[6] = f2bf16(v1.z); r.us[7] = f2bf16(v1.w);
    *(u32x4*)(wb2 + (size_t)chunk * OUT_F * 8 + o * 8) = *(u32x4*)&r;
}

// ---------------- fused basis-expansion GEMM ----------------
// 8 waves = 4 N-cols (wc) x 2 K-halves (ks); wave tile 32M x 64N x 64K/step.
// B single-set global->reg (L2 latency covered by stageA VALU); x/tab E/O
// cross-body prefetch; A through 16 KB LDS double buffer, 16-chunk XOR swz.
// LDS-only raw barrier per step (R9-proven); 2 independent blocks/CU.
__global__ __launch_bounds__(NTHREADS, 4)
void fused_tanh_gemm(const float* __restrict__ x,
                     const unsigned short* __restrict__ Wb,   // transposed bf16
                     const float4* __restrict__ Tab,
                     float* __restrict__ out) {
    __shared__ __align__(16) char smem[32 * 1024];
    unsigned short* As0 = (unsigned short*)smem;          // [32][128] bf16, 8 KB
    unsigned short* As1 = As0 + 32 * 128;
    float* ldsTab = (float*)(smem + 16384);               // 512 x float4 = 8 KB
    float* red    = (float*)smem;                         // epilogue alias 32 KB

    const int tid  = threadIdx.x;
    const int wid  = tid >> 6;
    const int lane = tid & 63;

    // XCD mapping: xcd&1 picks N-half (2MB Wb panel pinned per XCD's L2)
    const int bid = blockIdx.x;            // 512 blocks
    const int xcd = bid & 7;
    const int rix = bid >> 3;              // 0..63
    const int bn0 = (xcd & 1) * BN;
    const int bm0 = (((xcd >> 1) * 64) + rix) * BM;   // 256 M-strips of 32

    // wave roles
    const int wc = wid & 3;                // N column 0..3
    const int ks = wid >> 2;               // K half 0..1
    const int fr = lane & 15;
    const int fq = lane >> 4;              // 0..3

    // A staging coords: one feature-chunk (8 basis vals) per thread
    const int arow = tid >> 4;             // 0..31
    const int f    = tid & 15;             // feature-in-step 0..15
    const float* xrowf = x + (size_t)(bm0 + arow) * IN_F + f;

    const int aw = arow * 128 + ((f ^ (arow & 15)) * 8);        // A-write (elems)
    // A-read lane offsets (elems): chunk-in-step = ks*8 + kf*4 + fq, XOR row&15=fr
    const int la0 = fr * 128 + (((ks * 8 + 0 + fq) ^ fr) * 8);  // kf=0
    const int la1 = fr * 128 + (((ks * 8 + 4 + fq) ^ fr) * 8);  // kf=1
    // mi=1 adds +2048 elems (4096 B)

    // B bases (transposed layout): chunk = t*16 + ks*8 + kf*4 + fq,
    // col = bn0 + wc*64 + ni*16 + fr; elem = (chunk*512 + col)*8
    const unsigned short* bq0 =
        Wb + ((size_t)(ks * 8 + 0 + fq) * OUT_F + bn0 + wc * 64 + fr) * 8;
    const unsigned short* bq1 =
        Wb + ((size_t)(ks * 8 + 4 + fq) * OUT_F + bn0 + wc * 64 + fr) * 8;
    // per step: +16 chunks = +65536 elems; per ni: +128 elems (256 B)

    auto stageA = [&](unsigned short* bufWr, float xv, f32x4 tb) {
        float e = __builtin_amdgcn_exp2f(tb[0] * xv + tb[1]);
        float rr = tb[2];
        float s0 = __builtin_amdgcn_rcpf(1.0f + e); e *= rr;
        float s1 = __builtin_amdgcn_rcpf(1.0f + e); e *= rr;
        float s2 = __builtin_amdgcn_rcpf(1.0f + e); e *= rr;
        float s3 = __builtin_amdgcn_rcpf(1.0f + e); e *= rr;
        float s4 = __builtin_amdgcn_rcpf(1.0f + e); e *= rr;
        float s5 = __builtin_amdgcn_rcpf(1.0f + e); e *= rr;
        float s6 = __builtin_amdgcn_rcpf(1.0f + e); e *= rr;
        float s7 = __builtin_amdgcn_rcpf(1.0f + e);
        u32x4 pk;
        pk[0] = cvtpk(s0, s1); pk[1] = cvtpk(s2, s3);
        pk[2] = cvtpk(s4, s5); pk[3] = cvtpk(s6, s7);
        *(u32x4*)(bufWr + aw) = pk;                   // one ds_write_b128
    };

    f32x4 acc[2][4];
    #pragma unroll
    for (int mi = 0; mi < 2; ++mi)
        #pragma unroll
        for (int ni = 0; ni < 4; ++ni)
            acc[mi][ni] = (f32x4){0.f, 0.f, 0.f, 0.f};

    // ---- prologue ----
    *(float4*)(ldsTab + tid * 4) = Tab[tid];          // tables -> LDS
    __syncthreads();
    {
        f32x4 tb0 = *(const f32x4*)(ldsTab + f * 4);  // step-0 feature = f
        stageA(As0, xrowf[0], tb0);
    }
    // x/tab for step 1 -> E set
    float xE = xrowf[16];
    f32x4 tE = *(const f32x4*)(ldsTab + (16 + f) * 4);
    asm volatile("s_waitcnt lgkmcnt(0)" ::: "memory");
    __builtin_amdgcn_sched_barrier(0);
    __builtin_amdgcn_s_barrier();
    __builtin_amdgcn_sched_barrier(0);

    float xO; f32x4 tO;

    // ---- main loop: 16 double-bodies, one LDS-only barrier per body ----
    #define BODY(T, bufRd, bufWr, xc, tc, xn, tn)                              \
    {                                                                          \
        const int t_ = (T);                                                    \
        /* A-frag ds_reads for step t */                                       \
        short8 af00 = *(const short8*)((bufRd) + la0);          /* mi0 kf0 */  \
        short8 af01 = *(const short8*)((bufRd) + la1);          /* mi0 kf1 */  \
        short8 af10 = *(const short8*)((bufRd) + la0 + 2048);   /* mi1 kf0 */  \
        short8 af11 = *(const short8*)((bufRd) + la1 + 2048);   /* mi1 kf1 */  \
        /* B(t) loads, single set, consumed this body */                       \
        const unsigned short* bp0 = bq0 + ((size_t)t_ << 16);                  \
        const unsigned short* bp1 = bq1 + ((size_t)t_ << 16);                  \
        short8 b00 = *(const short8*)(bp0 + 0 * 128);                          \
        short8 b01 = *(const short8*)(bp0 + 1 * 128);                          \
        short8 b02 = *(const short8*)(bp0 + 2 * 128);                          \
        short8 b03 = *(const short8*)(bp0 + 3 * 128);                          \
        short8 b10 = *(const short8*)(bp1 + 0 * 128);                          \
        short8 b11 = *(const short8*)(bp1 + 1 * 128);                          \
        short8 b12 = *(const short8*)(bp1 + 2 * 128);                          \
        short8 b13 = *(const short8*)(bp1 + 3 * 128);                          \
        /* x/tab(t+2) -> other E/O set */                                      \
        const int k2 = (t_ + 2 > 31) ? 31 : (t_ + 2);                          \
        xn = xrowf[k2 * 16];                                                   \
        tn = *(const f32x4*)(ldsTab + (k2 * 16 + f) * 4);                      \
        /* build A(t+1): VALU chain covers B L2 latency */                     \
        stageA((bufWr), xc, tc);                                               \
        /* MFMA: kf0 cluster then kf1 (b1x may arrive later) */                \
        __builtin_amdgcn_s_setprio(1);                                         \
        acc[0][0] = __builtin_amdgcn_mfma_f32_16x16x32_bf16(af00, b00, acc[0][0], 0, 0, 0); \
        acc[0][1] = __builtin_amdgcn_mfma_f32_16x16x32_bf16(af00, b01, acc[0][1], 0, 0, 0); \
        acc[0][2] = __builtin_amdgcn_mfma_f32_16x16x32_bf16(af00, b02, acc[0][2], 0, 0, 0); \
        acc[0][3] = __builtin_amdgcn_mfma_f32_16x16x32_bf16(af00, b03, acc[0][3], 0, 0, 0); \
        acc[1][0] = __builtin_amdgcn_mfma_f32_16x16x32_bf16(af10, b00, acc[1][0], 0, 0, 0); \
        acc[1][1] = __builtin_amdgcn_mfma_f32_16x16x32_bf16(af10, b01, acc[1][1], 0, 0, 0); \
        acc[1][2] = __builtin_amdgcn_mfma_f32_16x16x32_bf16(af10, b02, acc[1][2], 0, 0, 0); \
        acc[1][3] = __builtin_amdgcn_mfma_f32_16x16x32_bf16(af10, b03, acc[1][3], 0, 0, 0); \
        acc[0][0] = __builtin_amdgcn_mfma_f32_16x16x32_bf16(af01, b10, acc[0][0], 0, 0, 0); \
        acc[0][1] = __builtin_amdgcn_mfma_f32_16x16x32_bf16(af01, b11, acc[0][1], 0, 0, 0); \
        acc[0][2] = __builtin_amdgcn_mfma_f32_16x16x32_bf16(af01, b12, acc[0][2], 0, 0, 0); \
        acc[0][3] = __builtin_amdgcn_mfma_f32_16x16x32_bf16(af01, b13, acc[0][3], 0, 0, 0); \
        acc[1][0] = __builtin_amdgcn_mfma_f32_16x16x32_bf16(af11, b10, acc[1][0], 0, 0, 0); \
        acc[1][1] = __builtin_amdgcn_mfma_f32_16x16x32_bf16(af11, b11, acc[1][1], 0, 0, 0); \
        acc[1][2] = __builtin_amdgcn_mfma_f32_16x16x32_bf16(af11, b12, acc[1][2], 0, 0, 0); \
        acc[1][3] = __builtin_amdgcn_mfma_f32_16x16x32_bf16(af11, b13, acc[1][3], 0, 0, 0); \
        __builtin_amdgcn_s_setprio(0);                                         \
        /* LDS-only fence; VMEM floats across the barrier */                   \
        asm volatile("s_waitcnt lgkmcnt(0)" ::: "memory");                     \
        __builtin_amdgcn_sched_barrier(0);                                     \
        __builtin_amdgcn_s_barrier();                                          \
        __builtin_amdgcn_sched_barrier(0);                                     \
    }

    #pragma unroll 1
    for (int it = 0; it < NSTEPS / 2; ++it) {
        int t = it * 2;
        BODY(t,     As0, As1, xE, tE, xO, tO);
        BODY(t + 1, As1, As0, xO, tO, xE, tE);
    }
    #undef BODY

    // ---- epilogue: reduce K-halves through LDS, store ----
    __syncthreads();
    if (ks == 1) {
        #pragma unroll
        for (int mi = 0; mi < 2; ++mi)
            #pragma unroll
            for (int ni = 0; ni < 4; ++ni) {
                f32x4 v = acc[mi][ni];
                #pragma unroll
                for (int j = 0; j < 4; ++j) {
                    int row = mi * 16 + fq * 4 + j;
                    int col = wc * 64 + ni * 16 + fr;
                    red[row * BN + col] = v[j];
                }
            }
    }
    __syncthreads();
    if (ks == 0) {
        #pragma unroll
        for (int mi = 0; mi < 2; ++mi)
            #pragma unroll
            for (int ni = 0; ni < 4; ++ni) {
                f32x4 v = acc[mi][ni];
                #pragma unroll
                for (int j = 0; j < 4; ++j) {
                    int row = mi * 16 + fq * 4 + j;
                    int col = wc * 64 + ni * 16 + fr;
                    float s = v[j] + red[row * BN + col];
                    out[(size_t)(bm0 + row) * OUT_F + bn0 + col] = s;
                }
            }
    }
}

// ---------------- launcher ----------------
extern "C" void kernel_launch(void* const* d_in, const int* in_sizes, int n_in,
                              void* d_out, int out_size, void* d_ws, size_t ws_size,
                              hipStream_t stream) {
    const float* x         = (const float*)d_in[0];
    const float* coeffs    = (const float*)d_in[1];
    const float* raw_alpha = (const float*)d_in[2];
    const float* beta      = (const float*)d_in[3];
    const float* centers   = (const float*)d_in[4];
    const float* slopes    = (const float*)d_in[5];
    float* out = (float*)d_out;

    // ws layout: Wb2 bf16 transposed [512][512][8] = 4 MB, then Tab = 8 KB
    unsigned short* Wb2 = (unsigned short*)d_ws;
    float4* Tab = (float4*)((char*)d_ws + (size_t)OUT_F * KDIM * 2);

    prep_tabs<<<dim3((IN_F + 255) / 256), dim3(256), 0, stream>>>(
        raw_alpha, beta, centers, slopes, Tab);

    prep_wbt<<<dim3(262144 / 256), dim3(256), 0, stream>>>(coeffs, Wb2);

    fused_tanh_gemm<<<dim3((BATCH / BM) * (OUT_F / BN)), dim3(NTHREADS), 0, stream>>>(
        x, Wb2, Tab, out);
}